// Round 3
// baseline (53.512 us; speedup 1.0000x reference)
//
#include <hip/hip_runtime.h>

// Problem constants (from reference):
//   X_train: [1024, 128] f32; coalition_vectors: [64, 128] f32 (0/1); instance: [8, 128] f32
//   out0 = filled_X [1, M*C*N + M, 128] = [1, 524296, 128]
//   out1 = instance [8, 128]
//   d_out = out0 flat ++ out1 flat = 67,110,912 floats (~268 MB)
//
// Pure streaming-write kernel. R1: 43.0 us = 6.24 TB/s. Memset reference on
// same chip: 6.9-7.1 TB/s pure-write. This revision: grid-stride @ 2048 blocks
// (amortize per-block overhead over ~32 float4/thread) + nontemporal stores
// (don't thrash L2, which caches the tiny read set). R2 fix: use clang
// ext_vector_type — __builtin_nontemporal_store rejects HIP_vector_type.

#define N_TRAIN 1024
#define D_FEAT  128
#define N_COAL  64
#define N_INST  8

using f32x4 = __attribute__((ext_vector_type(4))) float;

constexpr int ROWS_MAIN  = N_INST * N_COAL * N_TRAIN;   // 524288 rows of where-select
constexpr int ROWS_TOTAL = ROWS_MAIN + 2 * N_INST;      // + 8 (concat tail) + 8 (out1) = 524304
constexpr int Q_PER_ROW  = D_FEAT / 4;                  // 32 float4 per row
constexpr int TOTAL_Q    = ROWS_TOTAL * Q_PER_ROW;      // 16,777,728 float4 stores
constexpr int MAIN_Q     = ROWS_MAIN * Q_PER_ROW;       // 16,777,216 (pow2 — no bound check in hot loop)

__global__ void __launch_bounds__(256) shap_fill_kernel(
        const f32x4* __restrict__ X4,     // [1024*32]
        const f32x4* __restrict__ coal4,  // [64*32]
        const f32x4* __restrict__ inst4,  // [8*32]
        f32x4* __restrict__ out4) {
    const int stride = gridDim.x * blockDim.x;          // 2048*256 = 524288
    int i = blockIdx.x * blockDim.x + threadIdx.x;

    // Main region: i < 16,777,216. stride divides MAIN_Q exactly (32 iters),
    // so no per-iteration bounds check needed.
    for (; i < MAIN_Q; i += stride) {
        const int row = i >> 5;
        const int q   = i & 31;
        const int n   = row & (N_TRAIN - 1);
        const int c   = (row >> 10) & (N_COAL - 1);
        const int m   = row >> 16;

        const f32x4 mk = coal4[c * Q_PER_ROW + q];
        const f32x4 iv = inst4[m * Q_PER_ROW + q];
        const f32x4 xv = X4[n * Q_PER_ROW + q];

        f32x4 v;
        v.x = (mk.x != 0.0f) ? iv.x : xv.x;
        v.y = (mk.y != 0.0f) ? iv.y : xv.y;
        v.z = (mk.z != 0.0f) ? iv.z : xv.z;
        v.w = (mk.w != 0.0f) ? iv.w : xv.w;
        __builtin_nontemporal_store(v, &out4[i]);
    }

    // Tail: 512 float4 (16 instance-copy rows: 8 concat-tail + 8 out1).
    if (i < TOTAL_Q) {
        const int row = (i >> 5) - ROWS_MAIN;
        const int q   = i & 31;
        const int m   = row & (N_INST - 1);
        const f32x4 t = inst4[m * Q_PER_ROW + q];
        __builtin_nontemporal_store(t, &out4[i]);
    }
}

extern "C" void kernel_launch(void* const* d_in, const int* in_sizes, int n_in,
                              void* d_out, int out_size, void* d_ws, size_t ws_size,
                              hipStream_t stream) {
    const f32x4* X4     = (const f32x4*)d_in[0];  // X_train
    const f32x4* coal4  = (const f32x4*)d_in[1];  // coalition_vectors
    const f32x4* inst4  = (const f32x4*)d_in[2];  // instance
    f32x4* out4 = (f32x4*)d_out;

    shap_fill_kernel<<<2048, 256, 0, stream>>>(X4, coal4, inst4, out4);
}

// Round 4
// 45.635 us; speedup vs baseline: 1.1726x; 1.1726x over previous
//
#include <hip/hip_runtime.h>

// Problem constants (from reference):
//   X_train: [1024, 128] f32; coalition_vectors: [64, 128] f32 (0/1); instance: [8, 128] f32
//   out0 = filled_X [1, M*C*N + M, 128] = [1, 524296, 128]
//   out1 = instance [8, 128]
//   d_out = out0 flat ++ out1 flat = 67,110,912 floats (~268 MB)
//
// R1 (flat grid, plain stores): 43.0 us = 6.24 TB/s write-equivalent.
// R3 (grid-stride + nt): 53.5 us — regression; grid-stride scatters the
// in-flight write window across all 268 MB (HBM page thrash). This round:
// R1's flat-grid sweep + nontemporal stores ONLY (isolate nt). Goal: stop
// the write stream from evicting X_train out of per-XCD L2 (~30 MB of HBM
// re-fetch at R1's timing arithmetic).

#define N_TRAIN 1024
#define D_FEAT  128
#define N_COAL  64
#define N_INST  8

using f32x4 = __attribute__((ext_vector_type(4))) float;

constexpr int ROWS_MAIN  = N_INST * N_COAL * N_TRAIN;   // 524288 rows of where-select
constexpr int ROWS_TOTAL = ROWS_MAIN + 2 * N_INST;      // + 8 (concat tail) + 8 (out1) = 524304
constexpr int Q_PER_ROW  = D_FEAT / 4;                  // 32 float4 per row
constexpr int TOTAL_Q    = ROWS_TOTAL * Q_PER_ROW;      // 16,777,728 float4 stores

__global__ void shap_fill_kernel(const f32x4* __restrict__ X4,     // [1024*32]
                                 const f32x4* __restrict__ coal4,  // [64*32]
                                 const f32x4* __restrict__ inst4,  // [8*32]
                                 f32x4* __restrict__ out4) {
    int i = blockIdx.x * blockDim.x + threadIdx.x;
    if (i >= TOTAL_Q) return;

    const int row = i >> 5;      // / Q_PER_ROW
    const int q   = i & 31;      // float4 index within the 128-float row

    f32x4 v;
    if (row < ROWS_MAIN) {
        // row = m*65536 + c*1024 + n  (all pow2 -> bit ops)
        const int n = row & (N_TRAIN - 1);
        const int c = (row >> 10) & (N_COAL - 1);
        const int m = row >> 16;

        const f32x4 mk = coal4[c * Q_PER_ROW + q];
        const f32x4 iv = inst4[m * Q_PER_ROW + q];
        const f32x4 xv = X4[n * Q_PER_ROW + q];

        v.x = (mk.x != 0.0f) ? iv.x : xv.x;
        v.y = (mk.y != 0.0f) ? iv.y : xv.y;
        v.z = (mk.z != 0.0f) ? iv.z : xv.z;
        v.w = (mk.w != 0.0f) ? iv.w : xv.w;
    } else {
        // Tail: rows [524288,524296) = instance appended to filled_X;
        //       rows [524296,524304) = output 1 (instance again).
        const int m = (row - ROWS_MAIN) & (N_INST - 1);
        v = inst4[m * Q_PER_ROW + q];
    }
    __builtin_nontemporal_store(v, &out4[i]);
}

extern "C" void kernel_launch(void* const* d_in, const int* in_sizes, int n_in,
                              void* d_out, int out_size, void* d_ws, size_t ws_size,
                              hipStream_t stream) {
    const f32x4* X4     = (const f32x4*)d_in[0];  // X_train
    const f32x4* coal4  = (const f32x4*)d_in[1];  // coalition_vectors
    const f32x4* inst4  = (const f32x4*)d_in[2];  // instance
    f32x4* out4 = (f32x4*)d_out;

    const int threads = 256;
    const int blocks  = (TOTAL_Q + threads - 1) / threads;  // 65538
    shap_fill_kernel<<<blocks, threads, 0, stream>>>(X4, coal4, inst4, out4);
}

// Round 5
// 44.951 us; speedup vs baseline: 1.1905x; 1.0152x over previous
//
#include <hip/hip_runtime.h>

// Problem constants (from reference):
//   X_train: [1024, 128] f32; coalition_vectors: [64, 128] f32 (0/1); instance: [8, 128] f32
//   out0 = filled_X [1, M*C*N + M, 128] = [1, 524296, 128]
//   out1 = instance [8, 128]
//   d_out = out0 flat ++ out1 flat = 67,110,912 floats (~268 MB)
//
// Ladder: R1 flat+plain = 43.0 us (6.24 TB/s). R3 grid-stride+nt = 53.5 (page
// scatter). R4 flat+nt = 45.6 (nt loses write-combining; reads were already
// L1/L2-resident). This round: R1 + 4 coalesced float4 stores per thread
// (block owns a compact 16 KB window; each store is still 1 KB/wave
// contiguous). Fewer blocks (16385), 4x store ILP, amortized index math.

#define N_TRAIN 1024
#define D_FEAT  128
#define N_COAL  64
#define N_INST  8

using f32x4 = __attribute__((ext_vector_type(4))) float;

constexpr int ROWS_MAIN  = N_INST * N_COAL * N_TRAIN;   // 524288 rows of where-select
constexpr int ROWS_TOTAL = ROWS_MAIN + 2 * N_INST;      // + 8 (concat tail) + 8 (out1) = 524304
constexpr int Q_PER_ROW  = D_FEAT / 4;                  // 32 float4 per row
constexpr int TOTAL_Q    = ROWS_TOTAL * Q_PER_ROW;      // 16,777,728 float4 stores
constexpr int VPT        = 4;                            // float4 per thread
constexpr int QPB        = 256 * VPT;                    // 1024 float4 per block

__device__ __forceinline__ f32x4 compute_q(int i,
                                           const f32x4* __restrict__ X4,
                                           const f32x4* __restrict__ coal4,
                                           const f32x4* __restrict__ inst4) {
    const int row = i >> 5;      // / Q_PER_ROW
    const int q   = i & 31;
    if (row < ROWS_MAIN) {
        const int n = row & (N_TRAIN - 1);
        const int c = (row >> 10) & (N_COAL - 1);
        const int m = row >> 16;
        const f32x4 mk = coal4[c * Q_PER_ROW + q];
        const f32x4 iv = inst4[m * Q_PER_ROW + q];
        const f32x4 xv = X4[n * Q_PER_ROW + q];
        f32x4 v;
        v.x = (mk.x != 0.0f) ? iv.x : xv.x;
        v.y = (mk.y != 0.0f) ? iv.y : xv.y;
        v.z = (mk.z != 0.0f) ? iv.z : xv.z;
        v.w = (mk.w != 0.0f) ? iv.w : xv.w;
        return v;
    }
    const int m = (row - ROWS_MAIN) & (N_INST - 1);
    return inst4[m * Q_PER_ROW + q];
}

__global__ void __launch_bounds__(256) shap_fill_kernel(
        const f32x4* __restrict__ X4,     // [1024*32]
        const f32x4* __restrict__ coal4,  // [64*32]
        const f32x4* __restrict__ inst4,  // [8*32]
        f32x4* __restrict__ out4) {
    const int base = blockIdx.x * QPB + threadIdx.x;

    if (base + 3 * 256 < TOTAL_Q) {
        // Full block: 4 coalesced stores, no per-store bound checks.
        f32x4 v0 = compute_q(base,           X4, coal4, inst4);
        f32x4 v1 = compute_q(base + 256,     X4, coal4, inst4);
        f32x4 v2 = compute_q(base + 512,     X4, coal4, inst4);
        f32x4 v3 = compute_q(base + 768,     X4, coal4, inst4);
        out4[base]       = v0;
        out4[base + 256] = v1;
        out4[base + 512] = v2;
        out4[base + 768] = v3;
    } else {
        #pragma unroll
        for (int j = 0; j < VPT; ++j) {
            const int i = base + j * 256;
            if (i < TOTAL_Q) out4[i] = compute_q(i, X4, coal4, inst4);
        }
    }
}

extern "C" void kernel_launch(void* const* d_in, const int* in_sizes, int n_in,
                              void* d_out, int out_size, void* d_ws, size_t ws_size,
                              hipStream_t stream) {
    const f32x4* X4     = (const f32x4*)d_in[0];  // X_train
    const f32x4* coal4  = (const f32x4*)d_in[1];  // coalition_vectors
    const f32x4* inst4  = (const f32x4*)d_in[2];  // instance
    f32x4* out4 = (f32x4*)d_out;

    const int blocks = (TOTAL_Q + QPB - 1) / QPB;  // 16385
    shap_fill_kernel<<<blocks, 256, 0, stream>>>(X4, coal4, inst4, out4);
}